// Round 16
// baseline (398.664 us; speedup 1.0000x reference)
//
#include <hip/hip_runtime.h>
#include <math.h>

// Problem constants
#define WIN   20
#define NWIN  399          // (4000-20)/10+1
#define NCH   2
#define TLEN  4000
#define NFR   798          // NCH*NWIN
#define KOPS  6
#define NB    2048
#define EPSV  1e-6f
#define RIDGE 1e-3f

// packed upper triangle index for 10x10, i<=j
#define TIX(i,j) ((i)*10 - (i)*((i)+1)/2 + (j))

// fast hardware transcendentals (~1e-7 rel err; output tolerance is 2.3e-2)
__device__ __forceinline__ float frcp(float x){float r;asm("v_rcp_f32 %0, %1":"=v"(r):"v"(x));return r;}
__device__ __forceinline__ float frsq(float x){float r;asm("v_rsq_f32 %0, %1":"=v"(r):"v"(x));return r;}
__device__ __forceinline__ float fsqr(float x){float r;asm("v_sqrt_f32 %0, %1":"=v"(r):"v"(x));return r;}

// ---------------------------------------------------------------- Jacobi 10x10
// Sequential cyclic Jacobi — PROVEN LOOP STRUCTURE. DO NOT MODIFY STRUCTURE:
// (a) nested compile-time p,q loops required (round 11: flattened constexpr
// order didn't unroll -> A/V in scratch, 11x slower). (b) DO NOT batch angles
// into arrays (rounds 8/9: spill, 4x slower). (c) DO NOT use 512-thread
// blocks or min-occupancy hints (rounds 2/5/6: 128-VGPR cap -> full spill).
// (d) cell-0 DIN=20 cand must NOT be fused per-thread (round 13: VGPR 256 +
// 10MB scratch).
// Rotation algebra (r-form, 2 SERIAL transcendental levels — sqrt(c2) and
// rsq(c2) both depend only on c2 so they issue in parallel; rsq(c2)=1/c
// replaces the serial rcp(c)):
//   d=(aqq-app)/2, mean=(app+aqq)/2, r2=d^2+apq^2, ir=rsq(r2),
//   c2=0.5+0.5|d|ir, c=sqrt(c2), icv=rsq(c2),
//   s=sign(d)*apq*(ir/2)*icv  [sign MULTIPLIES apq — round-14 bug was
//   copysignf(apq...,d) which REPLACED apq's sign],
//   app'=mean-sign(d)r, aqq'=mean+sign(d)r, r=r2*ir.
//   Verified: c^2+s^2=1, s^2=1-c2, annihilation exact.
// A: packed upper triangle (55), V: row-major 10x10 (100). On exit diag(A)=evals,
// columns of V are eigenvectors: A_orig = V diag V^T.
__device__ __forceinline__ void jacobi10(float* A, float* V) {
#pragma unroll
  for (int i = 0; i < 100; i++) V[i] = 0.f;
#pragma unroll
  for (int i = 0; i < 10; i++) V[i * 11] = 1.f;

  for (int sweep = 0; sweep < 7; ++sweep) {
    float off = 0.f, dia = 0.f;
#pragma unroll
    for (int p = 0; p < 10; p++) {
      float dd = A[TIX(p, p)];
      dia = fmaf(dd, dd, dia);
#pragma unroll
      for (int q = p + 1; q < 10; q++) { float o = A[TIX(p, q)]; off = fmaf(o, o, off); }
    }
    float fro2 = dia + 2.f * off;
    if (__ballot(off > 1e-11f * fro2) == 0ull) break;
    float skipthr = 1e-12f * fro2;

#pragma unroll
    for (int p = 0; p < 10; p++) {
#pragma unroll
      for (int q = p + 1; q < 10; q++) {
        float apq = A[TIX(p, q)];
        // skip rotation if every lane's pivot is negligible (late sweeps)
        if (__ballot(apq * apq > skipthr) == 0ull) continue;
        float app = A[TIX(p, p)];
        float aqq = A[TIX(q, q)];
        float d = 0.5f * (aqq - app);
        float mean = 0.5f * (app + aqq);
        float r2 = fmaf(d, d, apq * apq);
        bool rot = r2 > 1e-60f;
        float sgn = copysignf(1.0f, d);
        float ir = frsq(rot ? r2 : 1.0f);
        float c2 = fmaf(0.5f * fabsf(d), ir, 0.5f);  // c^2 >= 0.5
        float c = fsqr(c2);                          // sqrt(c2)   } independent,
        float icv = frsq(c2);                        // 1/sqrt(c2) } issue in parallel
        float s = sgn * apq * (0.5f * ir) * icv;     // sign(d)*apq/(2 r c)
        float rs = sgn * (r2 * ir);                  // sign(d)*r
        c = rot ? c : 1.0f;
        s = rot ? s : 0.0f;
#pragma unroll
        for (int j = 0; j < 10; j++) {
          if (j == p || j == q) continue;
          const int jp = (j < p) ? TIX(j, p) : TIX(p, j);
          const int jq = (j < q) ? TIX(j, q) : TIX(q, j);
          float ajp = A[jp], ajq = A[jq];
          A[jp] = fmaf(c, ajp, -s * ajq);
          A[jq] = fmaf(s, ajp, c * ajq);
        }
        A[TIX(p, p)] = rot ? (mean - rs) : app;
        A[TIX(q, q)] = rot ? (mean + rs) : aqq;
        A[TIX(p, q)] = rot ? 0.0f : apq;
#pragma unroll
        for (int i = 0; i < 10; i++) {
          float vip = V[i * 10 + p], viq = V[i * 10 + q];
          V[i * 10 + p] = fmaf(c, vip, -s * viq);
          V[i * 10 + q] = fmaf(s, vip, c * viq);
        }
      }
    }
  }
}

// ---------------------------------------------------------------- cov + stem
// hop-block decomposition: frame w = [b_w ; b_{w+1}] (10-blocks), w=0..398 per channel.
// C00 = T - b399 b399^T, C11 = T - b0 b0^T, C01 = Q, with
// T = sum_{i=0..399} b_i b_i^T, Q = sum_{i=0..398} b_i b_{i+1}^T (per channel).
// Output ROW-major [bc][400] (consumed by k_cand20 which stages per-block).
__global__ __launch_bounds__(256) void k_cov_stem(const float* __restrict__ x,
                                                  const float* __restrict__ Wst,
                                                  float* __restrict__ Sout) {
  __shared__ float xl[NCH * TLEN];
  __shared__ float pT[2][NCH][100];   // [seg][ch][d*10+e]
  __shared__ float pQ[2][NCH][100];
  __shared__ float bsum[NCH][10];
  __shared__ float b0v[NCH][10];
  __shared__ float b399v[NCH][10];
  __shared__ float cov[400];
  __shared__ float wst[400];
  __shared__ float tmp[400];
  int b = blockIdx.x, tid = threadIdx.x;
  const float4* xg = (const float4*)(x + (size_t)b * NCH * TLEN);
  float4* xl4 = (float4*)xl;
  for (int i = tid; i < NCH * TLEN / 4; i += 256) xl4[i] = xg[i];
  for (int i = tid; i < 400; i += 256) wst[i] = Wst[i];
  __syncthreads();

  if (tid < 200) {
    int grp = tid / 100;               // 0 = T, 1 = Q
    int c = (tid % 100) / 50;
    int r = tid % 50;
    int seg = r / 25, tile = r % 25;
    int d0 = (tile / 5) * 2, e0 = (tile % 5) * 2;
    const float* xc = xl + c * TLEN;
    int i0 = seg * 200;
    int i1 = grp ? ((seg == 1) ? 399 : 200) : (i0 + 200);
    int eoff = grp ? 10 : 0;
    float a00 = 0.f, a01 = 0.f, a10 = 0.f, a11 = 0.f;
    for (int i = i0; i < i1; i++) {
      float2 bd = *(const float2*)(xc + i * 10 + d0);
      float2 be = *(const float2*)(xc + i * 10 + eoff + e0);
      a00 = fmaf(bd.x, be.x, a00); a01 = fmaf(bd.x, be.y, a01);
      a10 = fmaf(bd.y, be.x, a10); a11 = fmaf(bd.y, be.y, a11);
    }
    float* dst = grp ? &pQ[seg][c][0] : &pT[seg][c][0];
    dst[d0 * 10 + e0] = a00;
    dst[d0 * 10 + e0 + 1] = a01;
    dst[(d0 + 1) * 10 + e0] = a10;
    dst[(d0 + 1) * 10 + e0 + 1] = a11;
  } else if (tid >= 200 && tid < 220) {
    int c = (tid - 200) / 10, d = (tid - 200) % 10;
    const float* xc = xl + c * TLEN;
    float s = 0.f;
    for (int i = 0; i < 400; i++) s += xc[i * 10 + d];
    bsum[c][d] = s;
    b0v[c][d] = xc[d];
    b399v[c][d] = xc[3990 + d];
  }
  __syncthreads();

  const float invN = 1.0f / (float)NFR;
  const float invN1 = 1.0f / (float)(NFR - 1);
  for (int o = tid; o < 400; o += 256) {
    int d = o / 20, e = o % 20;
    int dl = d % 10, el = e % 10;
    float s2;
    if (d < 10 && e < 10)
      s2 = (pT[0][0][dl * 10 + el] + pT[1][0][dl * 10 + el] - b399v[0][dl] * b399v[0][el]) +
           (pT[0][1][dl * 10 + el] + pT[1][1][dl * 10 + el] - b399v[1][dl] * b399v[1][el]);
    else if (d >= 10 && e >= 10)
      s2 = (pT[0][0][dl * 10 + el] + pT[1][0][dl * 10 + el] - b0v[0][dl] * b0v[0][el]) +
           (pT[0][1][dl * 10 + el] + pT[1][1][dl * 10 + el] - b0v[1][dl] * b0v[1][el]);
    else if (d < 10)
      s2 = pQ[0][0][dl * 10 + el] + pQ[1][0][dl * 10 + el] +
           pQ[0][1][dl * 10 + el] + pQ[1][1][dl * 10 + el];
    else
      s2 = pQ[0][0][el * 10 + dl] + pQ[1][0][el * 10 + dl] +
           pQ[0][1][el * 10 + dl] + pQ[1][1][el * 10 + dl];
    float md = (d < 10) ? (bsum[0][dl] - b399v[0][dl] + bsum[1][dl] - b399v[1][dl])
                        : (bsum[0][dl] - b0v[0][dl] + bsum[1][dl] - b0v[1][dl]);
    float me = (e < 10) ? (bsum[0][el] - b399v[0][el] + bsum[1][el] - b399v[1][el])
                        : (bsum[0][el] - b0v[0][el] + bsum[1][el] - b0v[1][el]);
    float v = (s2 - (float)NFR * (md * invN) * (me * invN)) * invN1;
    if (d == e) v += RIDGE;
    cov[o] = v;
  }
  __syncthreads();
  for (int o = tid; o < 400; o += 256) {
    int j = o / 20, l = o % 20;
    float acc = 0.f;
    for (int k2 = 0; k2 < 20; k2++) acc = fmaf(cov[j * 20 + k2], wst[k2 * 20 + l], acc);
    tmp[o] = acc;
  }
  __syncthreads();
  for (int o = tid; o < 400; o += 256) {
    int i = o / 20, l = o % 20;
    float acc = 0.f;
    for (int j = 0; j < 20; j++) acc = fmaf(wst[j * 20 + i], tmp[j * 20 + l], acc);
    if (i == l) acc += RIDGE;
    Sout[b * 400 + o] = acc;
  }
}

// ---------------------------------------------------------------- cand = W^T S W + ridge I (cell 0 only, DIN=20)
__global__ __launch_bounds__(256) void k_cand20(const float* __restrict__ Sin,
                                                const float* __restrict__ Wop,
                                                float* __restrict__ cand, int BC) {
  const int DIN = 20;
  __shared__ float Sl[DIN * DIN];
  __shared__ float Wl[12 * DIN * 10];
  __shared__ float Tl[12 * DIN * 10];
  int bc = blockIdx.x, tid = threadIdx.x;
  for (int i = tid; i < DIN * DIN; i += 256) Sl[i] = Sin[bc * DIN * DIN + i];
  for (int i = tid; i < 12 * DIN * 10; i += 256) Wl[i] = Wop[i];
  __syncthreads();
  for (int o = tid; o < 12 * DIN * 10; o += 256) {
    int mk = o / (DIN * 10);
    int r = o % (DIN * 10);
    int j = r / 10, n = r % 10;
    float acc = 0.f;
    for (int l = 0; l < DIN; l++) acc = fmaf(Sl[j * DIN + l], Wl[mk * DIN * 10 + l * 10 + n], acc);
    Tl[o] = acc;
  }
  __syncthreads();
  int NM = 12 * BC;
  for (int o = tid; o < 12 * 55; o += 256) {
    int mk = o / 55, t = o % 55;
    int t0 = t, i = 0;
    while (t0 >= 10 - i) { t0 -= 10 - i; i++; }
    int n = i + t0;
    float acc = 0.f;
    for (int j = 0; j < DIN; j++)
      acc = fmaf(Wl[mk * DIN * 10 + j * 10 + i], Tl[mk * DIN * 10 + j * 10 + n], acc);
    if (i == n) acc += RIDGE;
    cand[t * NM + mk * BC + bc] = acc;
  }
}

// ---------------------------------------------------------------- shared logm epilogue
__device__ __forceinline__ void logm_epilogue(float* A, float* V,
                                              float* __restrict__ cand, int NM, int mat) {
  float f[10];
#pragma unroll
  for (int r = 0; r < 10; r++) f[r] = __logf(fmaxf(A[TIX(r, r)], EPSV));
#pragma unroll
  for (int i = 0; i < 10; i++) {
    float w[10];
#pragma unroll
    for (int r = 0; r < 10; r++) w[r] = V[i * 10 + r] * f[r];
#pragma unroll
    for (int n = i; n < 10; n++) {
      float acc = 0.f;
#pragma unroll
      for (int r = 0; r < 10; r++) acc = fmaf(w[r], V[n * 10 + r], acc);
      cand[TIX(i, n) * NM + mat] = acc;
    }
  }
}

// ---------------------------------------------------------------- logm from cand buffer (cell 0)
__global__ __launch_bounds__(256) void k_logm(float* __restrict__ cand, int NM) {
  int mat = blockIdx.x * 256 + threadIdx.x;   // NM is a multiple of 256
  float A[55];
#pragma unroll
  for (int t = 0; t < 55; t++) A[t] = cand[t * NM + mat];
  float V[100];
  jacobi10(A, V);
  logm_epilogue(A, V, cand, NM, mat);
}

// ---------------------------------------------------------------- fused cand+logm (cells 1,2; DIN=10)
// S elem-major [e][BC] (written by k_expm) -> fully coalesced reads.
// 64-thread blocks (round 13: ~2% faster than 256, VGPR clean).
template <int BC>
__global__ __launch_bounds__(64) void k_candlogm(const float* __restrict__ Sin,
                                                 const float* __restrict__ Wop,
                                                 float* __restrict__ cand) {
  __shared__ float Wl[100];
  int tid = threadIdx.x;
  const int NM = 12 * BC;
  int mat = blockIdx.x * 64 + tid;
  int mk0 = (blockIdx.x * 64) / BC;      // 64 | BC -> uniform per block
  for (int i = tid; i < 100; i += 64) Wl[i] = Wop[mk0 * 100 + i];
  __syncthreads();
  int bc = mat % BC;
  const float* Sb = Sin + bc;            // elem-major: S[e*BC + bc]

  float U[100];
#pragma unroll
  for (int i = 0; i < 100; i++) U[i] = 0.f;
#pragma unroll
  for (int j = 0; j < 10; j++) {
    float sr[10];
#pragma unroll
    for (int l = 0; l < 10; l++) sr[l] = Sb[(j * 10 + l) * BC];
    float wr[10];
#pragma unroll
    for (int i = 0; i < 10; i++) wr[i] = Wl[j * 10 + i];
#pragma unroll
    for (int i = 0; i < 10; i++)
#pragma unroll
      for (int l = 0; l < 10; l++) U[i * 10 + l] = fmaf(wr[i], sr[l], U[i * 10 + l]);
  }
  float A[55];
#pragma unroll
  for (int t = 0; t < 55; t++) A[t] = 0.f;
#pragma unroll
  for (int i = 0; i < 10; i++) A[TIX(i, i)] = RIDGE;
#pragma unroll
  for (int l = 0; l < 10; l++) {
    float wr[10];
#pragma unroll
    for (int n = 0; n < 10; n++) wr[n] = Wl[l * 10 + n];
#pragma unroll
    for (int i = 0; i < 10; i++) {
      float u = U[i * 10 + l];
#pragma unroll
      for (int n = i; n < 10; n++) A[TIX(i, n)] = fmaf(u, wr[n], A[TIX(i, n)]);
    }
  }
  float V[100];
  jacobi10(A, V);
  logm_epilogue(A, V, cand, NM, mat);
}

// ---------------------------------------------------------------- sparsemax (per-thread, K=6)
__device__ __forceinline__ void sparsemax6(const float* __restrict__ a, int row, float* w) {
  float z[KOPS], zs[KOPS];
#pragma unroll
  for (int i = 0; i < KOPS; i++) { z[i] = a[row * KOPS + i]; zs[i] = z[i]; }
#pragma unroll
  for (int i = 0; i < KOPS; i++)
#pragma unroll
    for (int j = i + 1; j < KOPS; j++)
      if (zs[j] > zs[i]) { float tm = zs[i]; zs[i] = zs[j]; zs[j] = tm; }
  float acc = 0.f, zcp = 1.f; float cnt = 1.f;
#pragma unroll
  for (int i = 0; i < KOPS; i++) {
    acc += zs[i];
    if (1.0f + (float)(i + 1) * zs[i] > acc) { cnt = (float)(i + 1); zcp = acc; }
  }
  float tau = (zcp - 1.0f) / cnt;
#pragma unroll
  for (int i = 0; i < KOPS; i++) w[i] = fmaxf(z[i] - tau, 0.0f);
}

// ---------------------------------------------------------------- expm of weighted sum -> new S
// Output element-major [e][2*BC] -> fully coalesced stores, coalesced reads downstream.
template <int BC, int C>
__global__ __launch_bounds__(64) void k_expm(const float* __restrict__ L,
                                             const float* __restrict__ alphas, int row,
                                             float* __restrict__ Sout) {
  const int NM = 12 * BC;
  const int NE = 2 * BC;
  int id = blockIdx.x * 64 + threadIdx.x;  // id = m*BC + bc; 2*BC is a multiple of 64
  int m = id / BC;
  int bc = id % BC;
  float w[KOPS];
  sparsemax6(alphas, row, w);
  float A[55];
#pragma unroll
  for (int t = 0; t < 55; t++) {
    float acc = 0.f;
#pragma unroll
    for (int k2 = 0; k2 < KOPS; k2++) acc = fmaf(w[k2], L[t * NM + (m * KOPS + k2) * BC + bc], acc);
    A[t] = acc;
  }
  float V[100];
  jacobi10(A, V);
  float f[10];
#pragma unroll
  for (int r = 0; r < 10; r++) f[r] = __expf(A[TIX(r, r)]);
  int b = bc / C, c = bc % C;
  int idm = b * 2 * C + m * C + c;         // next stage's bc index
  float* out = Sout + idm;
#pragma unroll
  for (int i = 0; i < 10; i++) {
    float wv[10];
#pragma unroll
    for (int r = 0; r < 10; r++) wv[r] = V[i * 10 + r] * f[r];
#pragma unroll
    for (int n = i; n < 10; n++) {
      float acc = 0.f;
#pragma unroll
      for (int r = 0; r < 10; r++) acc = fmaf(wv[r], V[n * 10 + r], acc);
      out[(i * 10 + n) * NE] = acc;
      if (n != i) out[(n * 10 + i) * NE] = acc;
    }
  }
}

// ---------------------------------------------------------------- final: Z = sum w_k L_k fed straight to classifier
// Identity: out = logm(expm(Z)) = Z for symmetric Z — the final expm + logm
// (2x 16384 jacobis) cancel exactly. EPSV clamp inert (eigs >= log(RIDGE)).
__global__ __launch_bounds__(64) void k_final_direct(const float* __restrict__ L,
                                                     const float* __restrict__ alphas,
                                                     const float* __restrict__ Wc,
                                                     const float* __restrict__ bcv,
                                                     float* __restrict__ out) {
  const int BC = 4 * NB;
  const int NM = 12 * BC;
  int id = blockIdx.x * 64 + threadIdx.x;  // b*8+ch, total 16384
  int ch = id & 7;
  int b = id >> 3;
  int m = ch >> 2, j = ch & 3;
  int bc = b * 4 + j;
  float w[KOPS];
  sparsemax6(alphas, 2, w);
  const float* Lb = L + (size_t)(m * KOPS) * BC + bc;
  float Z[55];
#pragma unroll
  for (int t = 0; t < 55; t++) {
    float acc = 0.f;
#pragma unroll
    for (int k2 = 0; k2 < KOPS; k2++) acc = fmaf(w[k2], Lb[(size_t)t * NM + k2 * BC], acc);
    Z[t] = acc;
  }
  float acc[10];
#pragma unroll
  for (int c2 = 0; c2 < 10; c2++) acc[c2] = 0.f;
  const float* wbase = Wc + ch * 1000;     // row (ch*100 + i*10 + n), 10 cols
#pragma unroll
  for (int i = 0; i < 10; i++) {
#pragma unroll
    for (int n = 0; n < 10; n++) {
      float lv = (i <= n) ? Z[TIX(i, n)] : Z[TIX(n, i)];
      const float* wrow = wbase + (i * 10 + n) * 10;
#pragma unroll
      for (int h = 0; h < 5; h++) {
        float2 wc2 = *(const float2*)(wrow + 2 * h);
        acc[2 * h]     = fmaf(lv, wc2.x, acc[2 * h]);
        acc[2 * h + 1] = fmaf(lv, wc2.y, acc[2 * h + 1]);
      }
    }
  }
  // reduce over the 8 channel lanes (lanes id&7 within each group of 8)
#pragma unroll
  for (int mk = 1; mk < 8; mk <<= 1) {
#pragma unroll
    for (int c2 = 0; c2 < 10; c2++) acc[c2] += __shfl_xor(acc[c2], mk, 8);
  }
  if (ch == 0) {
#pragma unroll
    for (int c2 = 0; c2 < 10; c2++) out[b * 10 + c2] = acc[c2] + bcv[c2];
  }
}

// ---------------------------------------------------------------- launch
extern "C" void kernel_launch(void* const* d_in, const int* in_sizes, int n_in,
                              void* d_out, int out_size, void* d_ws, size_t ws_size,
                              hipStream_t stream) {
  const float* x      = (const float*)d_in[0];
  const float* Wst    = (const float*)d_in[1];
  const float* Wop0   = (const float*)d_in[2];
  const float* Wop1   = (const float*)d_in[3];
  const float* Wop2   = (const float*)d_in[4];
  const float* alphas = (const float*)d_in[5];
  const float* Wcls   = (const float*)d_in[6];
  const float* bcls   = (const float*)d_in[7];
  float* out = (float*)d_out;

  // workspace layout (floats): Sa(2048*800) | Sb(2048*800) | cand(55*12*2048*4)
  float* ws   = (float*)d_ws;
  float* Sa   = ws;
  float* Sb   = Sa + (size_t)NB * 800;
  float* cand = Sb + (size_t)NB * 800;

  k_cov_stem<<<NB, 256, 0, stream>>>(x, Wst, Sa);

  // cell 0: S (B,1,20,20) -> (B,2,10,10)   (DIN=20: split cand/logm path)
  k_cand20<<<NB, 256, 0, stream>>>(Sa, Wop0, cand, NB);
  k_logm<<<(12 * NB) / 256, 256, 0, stream>>>(cand, 12 * NB);
  k_expm<NB, 1><<<(2 * NB) / 64, 64, 0, stream>>>(cand, alphas, 0, Sb);

  // cell 1: (B,2,10,10) -> (B,4,10,10)   (fused cand+logm, elem-major S)
  k_candlogm<NB * 2><<<(12 * NB * 2) / 64, 64, 0, stream>>>(Sb, Wop1, cand);
  k_expm<NB * 2, 2><<<(4 * NB) / 64, 64, 0, stream>>>(cand, alphas, 1, Sa);

  // cell 2: (B,4,10,10) -> (B,8,10,10)
  k_candlogm<NB * 4><<<(12 * NB * 4) / 64, 64, 0, stream>>>(Sa, Wop2, cand);

  // final: logm(expm(Z)) = Z — weighted L-sum straight into classifier
  k_final_direct<<<(8 * NB) / 64, 64, 0, stream>>>(cand, alphas, Wcls, bcls, out);
}

// Round 17
// 396.058 us; speedup vs baseline: 1.0066x; 1.0066x over previous
//
#include <hip/hip_runtime.h>
#include <math.h>

// Problem constants
#define WIN   20
#define NWIN  399          // (4000-20)/10+1
#define NCH   2
#define TLEN  4000
#define NFR   798          // NCH*NWIN
#define KOPS  6
#define NB    2048
#define EPSV  1e-6f
#define RIDGE 1e-3f

// packed upper triangle index for 10x10, i<=j
#define TIX(i,j) ((i)*10 - (i)*((i)+1)/2 + (j))

// fast hardware transcendentals (~1e-7 rel err; output tolerance is 2.3e-2)
__device__ __forceinline__ float frcp(float x){float r;asm("v_rcp_f32 %0, %1":"=v"(r):"v"(x));return r;}
__device__ __forceinline__ float frsq(float x){float r;asm("v_rsq_f32 %0, %1":"=v"(r):"v"(x));return r;}
__device__ __forceinline__ float fsqr(float x){float r;asm("v_sqrt_f32 %0, %1":"=v"(r):"v"(x));return r;}

// ---------------------------------------------------------------- single Jacobi rotation
// template<P,Q> so ALL A/V indices are compile-time constants (round 11's
// constexpr-array order failed to fold -> scratch; templates cannot).
// Body identical to round-16 proven r-form (2 serial transcendental levels).
template <int P, int Q>
__device__ __forceinline__ void jrot(float* A, float* V, float skipthr) {
  float apq = A[TIX(P, Q)];
  // skip rotation if every lane's pivot is negligible (late sweeps)
  if (__ballot(apq * apq > skipthr) == 0ull) return;
  float app = A[TIX(P, P)];
  float aqq = A[TIX(Q, Q)];
  float d = 0.5f * (aqq - app);
  float mean = 0.5f * (app + aqq);
  float r2 = fmaf(d, d, apq * apq);
  bool rot = r2 > 1e-60f;
  float sgn = copysignf(1.0f, d);
  float ir = frsq(rot ? r2 : 1.0f);
  float c2 = fmaf(0.5f * fabsf(d), ir, 0.5f);  // c^2 >= 0.5
  float c = fsqr(c2);                          // sqrt(c2)   } independent,
  float icv = frsq(c2);                        // 1/sqrt(c2) } issue in parallel
  float s = sgn * apq * (0.5f * ir) * icv;     // sign(d)*apq/(2 r c)
  float rs = sgn * (r2 * ir);                  // sign(d)*r
  c = rot ? c : 1.0f;
  s = rot ? s : 0.0f;
#pragma unroll
  for (int j = 0; j < 10; j++) {
    if (j == P || j == Q) continue;
    const int jp = (j < P) ? TIX(j, P) : TIX(P, j);
    const int jq = (j < Q) ? TIX(j, Q) : TIX(Q, j);
    float ajp = A[jp], ajq = A[jq];
    A[jp] = fmaf(c, ajp, -s * ajq);
    A[jq] = fmaf(s, ajp, c * ajq);
  }
  A[TIX(P, P)] = rot ? (mean - rs) : app;
  A[TIX(Q, Q)] = rot ? (mean + rs) : aqq;
  A[TIX(P, Q)] = rot ? 0.0f : apq;
#pragma unroll
  for (int i = 0; i < 10; i++) {
    float vip = V[i * 10 + P], viq = V[i * 10 + Q];
    V[i * 10 + P] = fmaf(c, vip, -s * viq);
    V[i * 10 + Q] = fmaf(s, vip, c * viq);
  }
}

// ---------------------------------------------------------------- Jacobi 10x10
// TOURNAMENT rotation order via template instantiations: consecutive rotations
// act on disjoint (p,q), so rotation k+1's angle inputs (pivot+diagonals) are
// untouched by rotation k's apply — scheduler overlaps the ~45-cyc angle chain
// with the previous 76-FMA apply. Same 45 pairs/sweep; schedule correctness-
// validated in rounds 8/9/11.
// DO NOT: batch angles into arrays (rounds 8/9: spill); runtime-indexed pair
// arrays (round 11: scratch); 512-thread blocks / occupancy hints (rounds
// 2/5/6: 128-VGPR cap); per-thread DIN=20 cand fusion (round 13: spill).
// A: packed upper triangle (55), V: row-major 10x10 (100). On exit diag(A)=evals,
// columns of V are eigenvectors: A_orig = V diag V^T.
__device__ __forceinline__ void jacobi10(float* A, float* V) {
#pragma unroll
  for (int i = 0; i < 100; i++) V[i] = 0.f;
#pragma unroll
  for (int i = 0; i < 10; i++) V[i * 11] = 1.f;

  for (int sweep = 0; sweep < 7; ++sweep) {
    float off = 0.f, dia = 0.f;
#pragma unroll
    for (int p = 0; p < 10; p++) {
      float dd = A[TIX(p, p)];
      dia = fmaf(dd, dd, dia);
#pragma unroll
      for (int q = p + 1; q < 10; q++) { float o = A[TIX(p, q)]; off = fmaf(o, o, off); }
    }
    float fro2 = dia + 2.f * off;
    if (__ballot(off > 1e-11f * fro2) == 0ull) break;
    float t = 1e-12f * fro2;

    // round-robin tournament: 9 rounds x 5 disjoint pairs
    jrot<0,9>(A,V,t); jrot<1,8>(A,V,t); jrot<2,7>(A,V,t); jrot<3,6>(A,V,t); jrot<4,5>(A,V,t);
    jrot<0,8>(A,V,t); jrot<7,9>(A,V,t); jrot<1,6>(A,V,t); jrot<2,5>(A,V,t); jrot<3,4>(A,V,t);
    jrot<0,7>(A,V,t); jrot<6,8>(A,V,t); jrot<5,9>(A,V,t); jrot<1,4>(A,V,t); jrot<2,3>(A,V,t);
    jrot<0,6>(A,V,t); jrot<5,7>(A,V,t); jrot<4,8>(A,V,t); jrot<3,9>(A,V,t); jrot<1,2>(A,V,t);
    jrot<0,5>(A,V,t); jrot<4,6>(A,V,t); jrot<3,7>(A,V,t); jrot<2,8>(A,V,t); jrot<1,9>(A,V,t);
    jrot<0,4>(A,V,t); jrot<3,5>(A,V,t); jrot<2,6>(A,V,t); jrot<1,7>(A,V,t); jrot<8,9>(A,V,t);
    jrot<0,3>(A,V,t); jrot<2,4>(A,V,t); jrot<1,5>(A,V,t); jrot<6,9>(A,V,t); jrot<7,8>(A,V,t);
    jrot<0,2>(A,V,t); jrot<1,3>(A,V,t); jrot<4,9>(A,V,t); jrot<5,8>(A,V,t); jrot<6,7>(A,V,t);
    jrot<0,1>(A,V,t); jrot<2,9>(A,V,t); jrot<3,8>(A,V,t); jrot<4,7>(A,V,t); jrot<5,6>(A,V,t);
  }
}

// ---------------------------------------------------------------- cov + stem
// hop-block decomposition: frame w = [b_w ; b_{w+1}] (10-blocks), w=0..398 per channel.
// C00 = T - b399 b399^T, C11 = T - b0 b0^T, C01 = Q, with
// T = sum_{i=0..399} b_i b_i^T, Q = sum_{i=0..398} b_i b_{i+1}^T (per channel).
// Output ROW-major [bc][400] (consumed by k_cand20 which stages per-block).
__global__ __launch_bounds__(256) void k_cov_stem(const float* __restrict__ x,
                                                  const float* __restrict__ Wst,
                                                  float* __restrict__ Sout) {
  __shared__ float xl[NCH * TLEN];
  __shared__ float pT[2][NCH][100];   // [seg][ch][d*10+e]
  __shared__ float pQ[2][NCH][100];
  __shared__ float bsum[NCH][10];
  __shared__ float b0v[NCH][10];
  __shared__ float b399v[NCH][10];
  __shared__ float cov[400];
  __shared__ float wst[400];
  __shared__ float tmp[400];
  int b = blockIdx.x, tid = threadIdx.x;
  const float4* xg = (const float4*)(x + (size_t)b * NCH * TLEN);
  float4* xl4 = (float4*)xl;
  for (int i = tid; i < NCH * TLEN / 4; i += 256) xl4[i] = xg[i];
  for (int i = tid; i < 400; i += 256) wst[i] = Wst[i];
  __syncthreads();

  if (tid < 200) {
    int grp = tid / 100;               // 0 = T, 1 = Q
    int c = (tid % 100) / 50;
    int r = tid % 50;
    int seg = r / 25, tile = r % 25;
    int d0 = (tile / 5) * 2, e0 = (tile % 5) * 2;
    const float* xc = xl + c * TLEN;
    int i0 = seg * 200;
    int i1 = grp ? ((seg == 1) ? 399 : 200) : (i0 + 200);
    int eoff = grp ? 10 : 0;
    float a00 = 0.f, a01 = 0.f, a10 = 0.f, a11 = 0.f;
    for (int i = i0; i < i1; i++) {
      float2 bd = *(const float2*)(xc + i * 10 + d0);
      float2 be = *(const float2*)(xc + i * 10 + eoff + e0);
      a00 = fmaf(bd.x, be.x, a00); a01 = fmaf(bd.x, be.y, a01);
      a10 = fmaf(bd.y, be.x, a10); a11 = fmaf(bd.y, be.y, a11);
    }
    float* dst = grp ? &pQ[seg][c][0] : &pT[seg][c][0];
    dst[d0 * 10 + e0] = a00;
    dst[d0 * 10 + e0 + 1] = a01;
    dst[(d0 + 1) * 10 + e0] = a10;
    dst[(d0 + 1) * 10 + e0 + 1] = a11;
  } else if (tid >= 200 && tid < 220) {
    int c = (tid - 200) / 10, d = (tid - 200) % 10;
    const float* xc = xl + c * TLEN;
    float s = 0.f;
    for (int i = 0; i < 400; i++) s += xc[i * 10 + d];
    bsum[c][d] = s;
    b0v[c][d] = xc[d];
    b399v[c][d] = xc[3990 + d];
  }
  __syncthreads();

  const float invN = 1.0f / (float)NFR;
  const float invN1 = 1.0f / (float)(NFR - 1);
  for (int o = tid; o < 400; o += 256) {
    int d = o / 20, e = o % 20;
    int dl = d % 10, el = e % 10;
    float s2;
    if (d < 10 && e < 10)
      s2 = (pT[0][0][dl * 10 + el] + pT[1][0][dl * 10 + el] - b399v[0][dl] * b399v[0][el]) +
           (pT[0][1][dl * 10 + el] + pT[1][1][dl * 10 + el] - b399v[1][dl] * b399v[1][el]);
    else if (d >= 10 && e >= 10)
      s2 = (pT[0][0][dl * 10 + el] + pT[1][0][dl * 10 + el] - b0v[0][dl] * b0v[0][el]) +
           (pT[0][1][dl * 10 + el] + pT[1][1][dl * 10 + el] - b0v[1][dl] * b0v[1][el]);
    else if (d < 10)
      s2 = pQ[0][0][dl * 10 + el] + pQ[1][0][dl * 10 + el] +
           pQ[0][1][dl * 10 + el] + pQ[1][1][dl * 10 + el];
    else
      s2 = pQ[0][0][el * 10 + dl] + pQ[1][0][el * 10 + dl] +
           pQ[0][1][el * 10 + dl] + pQ[1][1][el * 10 + dl];
    float md = (d < 10) ? (bsum[0][dl] - b399v[0][dl] + bsum[1][dl] - b399v[1][dl])
                        : (bsum[0][dl] - b0v[0][dl] + bsum[1][dl] - b0v[1][dl]);
    float me = (e < 10) ? (bsum[0][el] - b399v[0][el] + bsum[1][el] - b399v[1][el])
                        : (bsum[0][el] - b0v[0][el] + bsum[1][el] - b0v[1][el]);
    float v = (s2 - (float)NFR * (md * invN) * (me * invN)) * invN1;
    if (d == e) v += RIDGE;
    cov[o] = v;
  }
  __syncthreads();
  for (int o = tid; o < 400; o += 256) {
    int j = o / 20, l = o % 20;
    float acc = 0.f;
    for (int k2 = 0; k2 < 20; k2++) acc = fmaf(cov[j * 20 + k2], wst[k2 * 20 + l], acc);
    tmp[o] = acc;
  }
  __syncthreads();
  for (int o = tid; o < 400; o += 256) {
    int i = o / 20, l = o % 20;
    float acc = 0.f;
    for (int j = 0; j < 20; j++) acc = fmaf(wst[j * 20 + i], tmp[j * 20 + l], acc);
    if (i == l) acc += RIDGE;
    Sout[b * 400 + o] = acc;
  }
}

// ---------------------------------------------------------------- cand = W^T S W + ridge I (cell 0 only, DIN=20)
__global__ __launch_bounds__(256) void k_cand20(const float* __restrict__ Sin,
                                                const float* __restrict__ Wop,
                                                float* __restrict__ cand, int BC) {
  const int DIN = 20;
  __shared__ float Sl[DIN * DIN];
  __shared__ float Wl[12 * DIN * 10];
  __shared__ float Tl[12 * DIN * 10];
  int bc = blockIdx.x, tid = threadIdx.x;
  for (int i = tid; i < DIN * DIN; i += 256) Sl[i] = Sin[bc * DIN * DIN + i];
  for (int i = tid; i < 12 * DIN * 10; i += 256) Wl[i] = Wop[i];
  __syncthreads();
  for (int o = tid; o < 12 * DIN * 10; o += 256) {
    int mk = o / (DIN * 10);
    int r = o % (DIN * 10);
    int j = r / 10, n = r % 10;
    float acc = 0.f;
    for (int l = 0; l < DIN; l++) acc = fmaf(Sl[j * DIN + l], Wl[mk * DIN * 10 + l * 10 + n], acc);
    Tl[o] = acc;
  }
  __syncthreads();
  int NM = 12 * BC;
  for (int o = tid; o < 12 * 55; o += 256) {
    int mk = o / 55, t = o % 55;
    int t0 = t, i = 0;
    while (t0 >= 10 - i) { t0 -= 10 - i; i++; }
    int n = i + t0;
    float acc = 0.f;
    for (int j = 0; j < DIN; j++)
      acc = fmaf(Wl[mk * DIN * 10 + j * 10 + i], Tl[mk * DIN * 10 + j * 10 + n], acc);
    if (i == n) acc += RIDGE;
    cand[t * NM + mk * BC + bc] = acc;
  }
}

// ---------------------------------------------------------------- shared logm epilogue
__device__ __forceinline__ void logm_epilogue(float* A, float* V,
                                              float* __restrict__ cand, int NM, int mat) {
  float f[10];
#pragma unroll
  for (int r = 0; r < 10; r++) f[r] = __logf(fmaxf(A[TIX(r, r)], EPSV));
#pragma unroll
  for (int i = 0; i < 10; i++) {
    float w[10];
#pragma unroll
    for (int r = 0; r < 10; r++) w[r] = V[i * 10 + r] * f[r];
#pragma unroll
    for (int n = i; n < 10; n++) {
      float acc = 0.f;
#pragma unroll
      for (int r = 0; r < 10; r++) acc = fmaf(w[r], V[n * 10 + r], acc);
      cand[TIX(i, n) * NM + mat] = acc;
    }
  }
}

// ---------------------------------------------------------------- logm from cand buffer (cell 0)
__global__ __launch_bounds__(256) void k_logm(float* __restrict__ cand, int NM) {
  int mat = blockIdx.x * 256 + threadIdx.x;   // NM is a multiple of 256
  float A[55];
#pragma unroll
  for (int t = 0; t < 55; t++) A[t] = cand[t * NM + mat];
  float V[100];
  jacobi10(A, V);
  logm_epilogue(A, V, cand, NM, mat);
}

// ---------------------------------------------------------------- fused cand+logm (cells 1,2; DIN=10)
// S elem-major [e][BC] (written by k_expm) -> fully coalesced reads.
// 64-thread blocks (round 13: ~2% faster than 256, VGPR clean).
template <int BC>
__global__ __launch_bounds__(64) void k_candlogm(const float* __restrict__ Sin,
                                                 const float* __restrict__ Wop,
                                                 float* __restrict__ cand) {
  __shared__ float Wl[100];
  int tid = threadIdx.x;
  const int NM = 12 * BC;
  int mat = blockIdx.x * 64 + tid;
  int mk0 = (blockIdx.x * 64) / BC;      // 64 | BC -> uniform per block
  for (int i = tid; i < 100; i += 64) Wl[i] = Wop[mk0 * 100 + i];
  __syncthreads();
  int bc = mat % BC;
  const float* Sb = Sin + bc;            // elem-major: S[e*BC + bc]

  float U[100];
#pragma unroll
  for (int i = 0; i < 100; i++) U[i] = 0.f;
#pragma unroll
  for (int j = 0; j < 10; j++) {
    float sr[10];
#pragma unroll
    for (int l = 0; l < 10; l++) sr[l] = Sb[(j * 10 + l) * BC];
    float wr[10];
#pragma unroll
    for (int i = 0; i < 10; i++) wr[i] = Wl[j * 10 + i];
#pragma unroll
    for (int i = 0; i < 10; i++)
#pragma unroll
      for (int l = 0; l < 10; l++) U[i * 10 + l] = fmaf(wr[i], sr[l], U[i * 10 + l]);
  }
  float A[55];
#pragma unroll
  for (int t = 0; t < 55; t++) A[t] = 0.f;
#pragma unroll
  for (int i = 0; i < 10; i++) A[TIX(i, i)] = RIDGE;
#pragma unroll
  for (int l = 0; l < 10; l++) {
    float wr[10];
#pragma unroll
    for (int n = 0; n < 10; n++) wr[n] = Wl[l * 10 + n];
#pragma unroll
    for (int i = 0; i < 10; i++) {
      float u = U[i * 10 + l];
#pragma unroll
      for (int n = i; n < 10; n++) A[TIX(i, n)] = fmaf(u, wr[n], A[TIX(i, n)]);
    }
  }
  float V[100];
  jacobi10(A, V);
  logm_epilogue(A, V, cand, NM, mat);
}

// ---------------------------------------------------------------- sparsemax (per-thread, K=6)
__device__ __forceinline__ void sparsemax6(const float* __restrict__ a, int row, float* w) {
  float z[KOPS], zs[KOPS];
#pragma unroll
  for (int i = 0; i < KOPS; i++) { z[i] = a[row * KOPS + i]; zs[i] = z[i]; }
#pragma unroll
  for (int i = 0; i < KOPS; i++)
#pragma unroll
    for (int j = i + 1; j < KOPS; j++)
      if (zs[j] > zs[i]) { float tm = zs[i]; zs[i] = zs[j]; zs[j] = tm; }
  float acc = 0.f, zcp = 1.f; float cnt = 1.f;
#pragma unroll
  for (int i = 0; i < KOPS; i++) {
    acc += zs[i];
    if (1.0f + (float)(i + 1) * zs[i] > acc) { cnt = (float)(i + 1); zcp = acc; }
  }
  float tau = (zcp - 1.0f) / cnt;
#pragma unroll
  for (int i = 0; i < KOPS; i++) w[i] = fmaxf(z[i] - tau, 0.0f);
}

// ---------------------------------------------------------------- expm of weighted sum -> new S
// Output element-major [e][2*BC] -> fully coalesced stores, coalesced reads downstream.
template <int BC, int C>
__global__ __launch_bounds__(64) void k_expm(const float* __restrict__ L,
                                             const float* __restrict__ alphas, int row,
                                             float* __restrict__ Sout) {
  const int NM = 12 * BC;
  const int NE = 2 * BC;
  int id = blockIdx.x * 64 + threadIdx.x;  // id = m*BC + bc; 2*BC is a multiple of 64
  int m = id / BC;
  int bc = id % BC;
  float w[KOPS];
  sparsemax6(alphas, row, w);
  float A[55];
#pragma unroll
  for (int t = 0; t < 55; t++) {
    float acc = 0.f;
#pragma unroll
    for (int k2 = 0; k2 < KOPS; k2++) acc = fmaf(w[k2], L[t * NM + (m * KOPS + k2) * BC + bc], acc);
    A[t] = acc;
  }
  float V[100];
  jacobi10(A, V);
  float f[10];
#pragma unroll
  for (int r = 0; r < 10; r++) f[r] = __expf(A[TIX(r, r)]);
  int b = bc / C, c = bc % C;
  int idm = b * 2 * C + m * C + c;         // next stage's bc index
  float* out = Sout + idm;
#pragma unroll
  for (int i = 0; i < 10; i++) {
    float wv[10];
#pragma unroll
    for (int r = 0; r < 10; r++) wv[r] = V[i * 10 + r] * f[r];
#pragma unroll
    for (int n = i; n < 10; n++) {
      float acc = 0.f;
#pragma unroll
      for (int r = 0; r < 10; r++) acc = fmaf(wv[r], V[n * 10 + r], acc);
      out[(i * 10 + n) * NE] = acc;
      if (n != i) out[(n * 10 + i) * NE] = acc;
    }
  }
}

// ---------------------------------------------------------------- final: Z = sum w_k L_k fed straight to classifier
// Identity: out = logm(expm(Z)) = Z for symmetric Z — the final expm + logm
// (2x 16384 jacobis) cancel exactly. EPSV clamp inert (eigs >= log(RIDGE)).
__global__ __launch_bounds__(64) void k_final_direct(const float* __restrict__ L,
                                                     const float* __restrict__ alphas,
                                                     const float* __restrict__ Wc,
                                                     const float* __restrict__ bcv,
                                                     float* __restrict__ out) {
  const int BC = 4 * NB;
  const int NM = 12 * BC;
  int id = blockIdx.x * 64 + threadIdx.x;  // b*8+ch, total 16384
  int ch = id & 7;
  int b = id >> 3;
  int m = ch >> 2, j = ch & 3;
  int bc = b * 4 + j;
  float w[KOPS];
  sparsemax6(alphas, 2, w);
  const float* Lb = L + (size_t)(m * KOPS) * BC + bc;
  float Z[55];
#pragma unroll
  for (int t = 0; t < 55; t++) {
    float acc = 0.f;
#pragma unroll
    for (int k2 = 0; k2 < KOPS; k2++) acc = fmaf(w[k2], Lb[(size_t)t * NM + k2 * BC], acc);
    Z[t] = acc;
  }
  float acc[10];
#pragma unroll
  for (int c2 = 0; c2 < 10; c2++) acc[c2] = 0.f;
  const float* wbase = Wc + ch * 1000;     // row (ch*100 + i*10 + n), 10 cols
#pragma unroll
  for (int i = 0; i < 10; i++) {
#pragma unroll
    for (int n = 0; n < 10; n++) {
      float lv = (i <= n) ? Z[TIX(i, n)] : Z[TIX(n, i)];
      const float* wrow = wbase + (i * 10 + n) * 10;
#pragma unroll
      for (int h = 0; h < 5; h++) {
        float2 wc2 = *(const float2*)(wrow + 2 * h);
        acc[2 * h]     = fmaf(lv, wc2.x, acc[2 * h]);
        acc[2 * h + 1] = fmaf(lv, wc2.y, acc[2 * h + 1]);
      }
    }
  }
  // reduce over the 8 channel lanes (lanes id&7 within each group of 8)
#pragma unroll
  for (int mk = 1; mk < 8; mk <<= 1) {
#pragma unroll
    for (int c2 = 0; c2 < 10; c2++) acc[c2] += __shfl_xor(acc[c2], mk, 8);
  }
  if (ch == 0) {
#pragma unroll
    for (int c2 = 0; c2 < 10; c2++) out[b * 10 + c2] = acc[c2] + bcv[c2];
  }
}

// ---------------------------------------------------------------- launch
extern "C" void kernel_launch(void* const* d_in, const int* in_sizes, int n_in,
                              void* d_out, int out_size, void* d_ws, size_t ws_size,
                              hipStream_t stream) {
  const float* x      = (const float*)d_in[0];
  const float* Wst    = (const float*)d_in[1];
  const float* Wop0   = (const float*)d_in[2];
  const float* Wop1   = (const float*)d_in[3];
  const float* Wop2   = (const float*)d_in[4];
  const float* alphas = (const float*)d_in[5];
  const float* Wcls   = (const float*)d_in[6];
  const float* bcls   = (const float*)d_in[7];
  float* out = (float*)d_out;

  // workspace layout (floats): Sa(2048*800) | Sb(2048*800) | cand(55*12*2048*4)
  float* ws   = (float*)d_ws;
  float* Sa   = ws;
  float* Sb   = Sa + (size_t)NB * 800;
  float* cand = Sb + (size_t)NB * 800;

  k_cov_stem<<<NB, 256, 0, stream>>>(x, Wst, Sa);

  // cell 0: S (B,1,20,20) -> (B,2,10,10)   (DIN=20: split cand/logm path)
  k_cand20<<<NB, 256, 0, stream>>>(Sa, Wop0, cand, NB);
  k_logm<<<(12 * NB) / 256, 256, 0, stream>>>(cand, 12 * NB);
  k_expm<NB, 1><<<(2 * NB) / 64, 64, 0, stream>>>(cand, alphas, 0, Sb);

  // cell 1: (B,2,10,10) -> (B,4,10,10)   (fused cand+logm, elem-major S)
  k_candlogm<NB * 2><<<(12 * NB * 2) / 64, 64, 0, stream>>>(Sb, Wop1, cand);
  k_expm<NB * 2, 2><<<(4 * NB) / 64, 64, 0, stream>>>(cand, alphas, 1, Sa);

  // cell 2: (B,4,10,10) -> (B,8,10,10)
  k_candlogm<NB * 4><<<(12 * NB * 4) / 64, 64, 0, stream>>>(Sa, Wop2, cand);

  // final: logm(expm(Z)) = Z — weighted L-sum straight into classifier
  k_final_direct<<<(8 * NB) / 64, 64, 0, stream>>>(cand, alphas, Wcls, bcls, out);
}

// Round 18
// 394.975 us; speedup vs baseline: 1.0093x; 1.0027x over previous
//
#include <hip/hip_runtime.h>
#include <math.h>

// Problem constants
#define WIN   20
#define NWIN  399          // (4000-20)/10+1
#define NCH   2
#define TLEN  4000
#define NFR   798          // NCH*NWIN
#define KOPS  6
#define NB    2048
#define EPSV  1e-6f
#define RIDGE 1e-3f

// packed upper triangle index for 10x10, i<=j
#define TIX(i,j) ((i)*10 - (i)*((i)+1)/2 + (j))

// fast hardware transcendentals (~1e-7 rel err; output tolerance is 2.3e-2)
__device__ __forceinline__ float frcp(float x){float r;asm("v_rcp_f32 %0, %1":"=v"(r):"v"(x));return r;}
__device__ __forceinline__ float frsq(float x){float r;asm("v_rsq_f32 %0, %1":"=v"(r):"v"(x));return r;}
__device__ __forceinline__ float fsqr(float x){float r;asm("v_sqrt_f32 %0, %1":"=v"(r):"v"(x));return r;}

// ---------------------------------------------------------------- single Jacobi rotation
// template<P,Q> so ALL A/V indices are compile-time constants (round 11's
// constexpr-array order failed to fold -> scratch; templates cannot).
// Body identical to round-16 proven r-form (2 serial transcendental levels).
template <int P, int Q>
__device__ __forceinline__ void jrot(float* A, float* V, float skipthr) {
  float apq = A[TIX(P, Q)];
  // skip rotation if every lane's pivot is negligible (late sweeps)
  if (__ballot(apq * apq > skipthr) == 0ull) return;
  float app = A[TIX(P, P)];
  float aqq = A[TIX(Q, Q)];
  float d = 0.5f * (aqq - app);
  float mean = 0.5f * (app + aqq);
  float r2 = fmaf(d, d, apq * apq);
  bool rot = r2 > 1e-60f;
  float sgn = copysignf(1.0f, d);
  float ir = frsq(rot ? r2 : 1.0f);
  float c2 = fmaf(0.5f * fabsf(d), ir, 0.5f);  // c^2 >= 0.5
  float c = fsqr(c2);                          // sqrt(c2)   } independent,
  float icv = frsq(c2);                        // 1/sqrt(c2) } issue in parallel
  float s = sgn * apq * (0.5f * ir) * icv;     // sign(d)*apq/(2 r c)
  float rs = sgn * (r2 * ir);                  // sign(d)*r
  c = rot ? c : 1.0f;
  s = rot ? s : 0.0f;
#pragma unroll
  for (int j = 0; j < 10; j++) {
    if (j == P || j == Q) continue;
    const int jp = (j < P) ? TIX(j, P) : TIX(P, j);
    const int jq = (j < Q) ? TIX(j, Q) : TIX(Q, j);
    float ajp = A[jp], ajq = A[jq];
    A[jp] = fmaf(c, ajp, -s * ajq);
    A[jq] = fmaf(s, ajp, c * ajq);
  }
  A[TIX(P, P)] = rot ? (mean - rs) : app;
  A[TIX(Q, Q)] = rot ? (mean + rs) : aqq;
  A[TIX(P, Q)] = rot ? 0.0f : apq;
#pragma unroll
  for (int i = 0; i < 10; i++) {
    float vip = V[i * 10 + P], viq = V[i * 10 + Q];
    V[i * 10 + P] = fmaf(c, vip, -s * viq);
    V[i * 10 + Q] = fmaf(s, vip, c * viq);
  }
}

// ---------------------------------------------------------------- Jacobi 10x10
// TOURNAMENT rotation order via template instantiations (round 17: equal-or-
// slightly-better than cyclic, clean codegen, VGPR 252 no spill).
// DO NOT: batch angles into arrays (rounds 8/9: spill); runtime-indexed pair
// arrays (round 11: scratch); 512-thread blocks / occupancy hints (rounds
// 2/5/6: 128-VGPR cap); per-thread DIN=20 cand fusion (round 13: spill).
// A: packed upper triangle (55), V: row-major 10x10 (100). On exit diag(A)=evals,
// columns of V are eigenvectors: A_orig = V diag V^T.
__device__ __forceinline__ void jacobi10(float* A, float* V) {
#pragma unroll
  for (int i = 0; i < 100; i++) V[i] = 0.f;
#pragma unroll
  for (int i = 0; i < 10; i++) V[i * 11] = 1.f;

  for (int sweep = 0; sweep < 7; ++sweep) {
    float off = 0.f, dia = 0.f;
#pragma unroll
    for (int p = 0; p < 10; p++) {
      float dd = A[TIX(p, p)];
      dia = fmaf(dd, dd, dia);
#pragma unroll
      for (int q = p + 1; q < 10; q++) { float o = A[TIX(p, q)]; off = fmaf(o, o, off); }
    }
    float fro2 = dia + 2.f * off;
    if (__ballot(off > 1e-11f * fro2) == 0ull) break;
    float t = 1e-12f * fro2;

    // round-robin tournament: 9 rounds x 5 disjoint pairs
    jrot<0,9>(A,V,t); jrot<1,8>(A,V,t); jrot<2,7>(A,V,t); jrot<3,6>(A,V,t); jrot<4,5>(A,V,t);
    jrot<0,8>(A,V,t); jrot<7,9>(A,V,t); jrot<1,6>(A,V,t); jrot<2,5>(A,V,t); jrot<3,4>(A,V,t);
    jrot<0,7>(A,V,t); jrot<6,8>(A,V,t); jrot<5,9>(A,V,t); jrot<1,4>(A,V,t); jrot<2,3>(A,V,t);
    jrot<0,6>(A,V,t); jrot<5,7>(A,V,t); jrot<4,8>(A,V,t); jrot<3,9>(A,V,t); jrot<1,2>(A,V,t);
    jrot<0,5>(A,V,t); jrot<4,6>(A,V,t); jrot<3,7>(A,V,t); jrot<2,8>(A,V,t); jrot<1,9>(A,V,t);
    jrot<0,4>(A,V,t); jrot<3,5>(A,V,t); jrot<2,6>(A,V,t); jrot<1,7>(A,V,t); jrot<8,9>(A,V,t);
    jrot<0,3>(A,V,t); jrot<2,4>(A,V,t); jrot<1,5>(A,V,t); jrot<6,9>(A,V,t); jrot<7,8>(A,V,t);
    jrot<0,2>(A,V,t); jrot<1,3>(A,V,t); jrot<4,9>(A,V,t); jrot<5,8>(A,V,t); jrot<6,7>(A,V,t);
    jrot<0,1>(A,V,t); jrot<2,9>(A,V,t); jrot<3,8>(A,V,t); jrot<4,7>(A,V,t); jrot<5,6>(A,V,t);
  }
}

// ---------------------------------------------------------------- cov + stem
// hop-block decomposition: frame w = [b_w ; b_{w+1}] (10-blocks), w=0..398 per channel.
// C00 = T - b399 b399^T, C11 = T - b0 b0^T, C01 = Q, with
// T = sum_{i=0..399} b_i b_i^T, Q = sum_{i=0..398} b_i b_{i+1}^T (per channel).
// Output ROW-major [bc][400] (consumed by k_cand20 which stages per-block).
__global__ __launch_bounds__(256) void k_cov_stem(const float* __restrict__ x,
                                                  const float* __restrict__ Wst,
                                                  float* __restrict__ Sout) {
  __shared__ float xl[NCH * TLEN];
  __shared__ float pT[2][NCH][100];   // [seg][ch][d*10+e]
  __shared__ float pQ[2][NCH][100];
  __shared__ float bsum[NCH][10];
  __shared__ float b0v[NCH][10];
  __shared__ float b399v[NCH][10];
  __shared__ float cov[400];
  __shared__ float wst[400];
  __shared__ float tmp[400];
  int b = blockIdx.x, tid = threadIdx.x;
  const float4* xg = (const float4*)(x + (size_t)b * NCH * TLEN);
  float4* xl4 = (float4*)xl;
  for (int i = tid; i < NCH * TLEN / 4; i += 256) xl4[i] = xg[i];
  for (int i = tid; i < 400; i += 256) wst[i] = Wst[i];
  __syncthreads();

  if (tid < 200) {
    int grp = tid / 100;               // 0 = T, 1 = Q
    int c = (tid % 100) / 50;
    int r = tid % 50;
    int seg = r / 25, tile = r % 25;
    int d0 = (tile / 5) * 2, e0 = (tile % 5) * 2;
    const float* xc = xl + c * TLEN;
    int i0 = seg * 200;
    int i1 = grp ? ((seg == 1) ? 399 : 200) : (i0 + 200);
    int eoff = grp ? 10 : 0;
    float a00 = 0.f, a01 = 0.f, a10 = 0.f, a11 = 0.f;
    for (int i = i0; i < i1; i++) {
      float2 bd = *(const float2*)(xc + i * 10 + d0);
      float2 be = *(const float2*)(xc + i * 10 + eoff + e0);
      a00 = fmaf(bd.x, be.x, a00); a01 = fmaf(bd.x, be.y, a01);
      a10 = fmaf(bd.y, be.x, a10); a11 = fmaf(bd.y, be.y, a11);
    }
    float* dst = grp ? &pQ[seg][c][0] : &pT[seg][c][0];
    dst[d0 * 10 + e0] = a00;
    dst[d0 * 10 + e0 + 1] = a01;
    dst[(d0 + 1) * 10 + e0] = a10;
    dst[(d0 + 1) * 10 + e0 + 1] = a11;
  } else if (tid >= 200 && tid < 220) {
    int c = (tid - 200) / 10, d = (tid - 200) % 10;
    const float* xc = xl + c * TLEN;
    float s = 0.f;
    for (int i = 0; i < 400; i++) s += xc[i * 10 + d];
    bsum[c][d] = s;
    b0v[c][d] = xc[d];
    b399v[c][d] = xc[3990 + d];
  }
  __syncthreads();

  const float invN = 1.0f / (float)NFR;
  const float invN1 = 1.0f / (float)(NFR - 1);
  for (int o = tid; o < 400; o += 256) {
    int d = o / 20, e = o % 20;
    int dl = d % 10, el = e % 10;
    float s2;
    if (d < 10 && e < 10)
      s2 = (pT[0][0][dl * 10 + el] + pT[1][0][dl * 10 + el] - b399v[0][dl] * b399v[0][el]) +
           (pT[0][1][dl * 10 + el] + pT[1][1][dl * 10 + el] - b399v[1][dl] * b399v[1][el]);
    else if (d >= 10 && e >= 10)
      s2 = (pT[0][0][dl * 10 + el] + pT[1][0][dl * 10 + el] - b0v[0][dl] * b0v[0][el]) +
           (pT[0][1][dl * 10 + el] + pT[1][1][dl * 10 + el] - b0v[1][dl] * b0v[1][el]);
    else if (d < 10)
      s2 = pQ[0][0][dl * 10 + el] + pQ[1][0][dl * 10 + el] +
           pQ[0][1][dl * 10 + el] + pQ[1][1][dl * 10 + el];
    else
      s2 = pQ[0][0][el * 10 + dl] + pQ[1][0][el * 10 + dl] +
           pQ[0][1][el * 10 + dl] + pQ[1][1][el * 10 + dl];
    float md = (d < 10) ? (bsum[0][dl] - b399v[0][dl] + bsum[1][dl] - b399v[1][dl])
                        : (bsum[0][dl] - b0v[0][dl] + bsum[1][dl] - b0v[1][dl]);
    float me = (e < 10) ? (bsum[0][el] - b399v[0][el] + bsum[1][el] - b399v[1][el])
                        : (bsum[0][el] - b0v[0][el] + bsum[1][el] - b0v[1][el]);
    float v = (s2 - (float)NFR * (md * invN) * (me * invN)) * invN1;
    if (d == e) v += RIDGE;
    cov[o] = v;
  }
  __syncthreads();
  for (int o = tid; o < 400; o += 256) {
    int j = o / 20, l = o % 20;
    float acc = 0.f;
    for (int k2 = 0; k2 < 20; k2++) acc = fmaf(cov[j * 20 + k2], wst[k2 * 20 + l], acc);
    tmp[o] = acc;
  }
  __syncthreads();
  for (int o = tid; o < 400; o += 256) {
    int i = o / 20, l = o % 20;
    float acc = 0.f;
    for (int j = 0; j < 20; j++) acc = fmaf(wst[j * 20 + i], tmp[j * 20 + l], acc);
    if (i == l) acc += RIDGE;
    Sout[b * 400 + o] = acc;
  }
}

// ---------------------------------------------------------------- cand = W^T S W + ridge I (cell 0 only, DIN=20)
__global__ __launch_bounds__(256) void k_cand20(const float* __restrict__ Sin,
                                                const float* __restrict__ Wop,
                                                float* __restrict__ cand, int BC) {
  const int DIN = 20;
  __shared__ float Sl[DIN * DIN];
  __shared__ float Wl[12 * DIN * 10];
  __shared__ float Tl[12 * DIN * 10];
  int bc = blockIdx.x, tid = threadIdx.x;
  for (int i = tid; i < DIN * DIN; i += 256) Sl[i] = Sin[bc * DIN * DIN + i];
  for (int i = tid; i < 12 * DIN * 10; i += 256) Wl[i] = Wop[i];
  __syncthreads();
  for (int o = tid; o < 12 * DIN * 10; o += 256) {
    int mk = o / (DIN * 10);
    int r = o % (DIN * 10);
    int j = r / 10, n = r % 10;
    float acc = 0.f;
    for (int l = 0; l < DIN; l++) acc = fmaf(Sl[j * DIN + l], Wl[mk * DIN * 10 + l * 10 + n], acc);
    Tl[o] = acc;
  }
  __syncthreads();
  int NM = 12 * BC;
  for (int o = tid; o < 12 * 55; o += 256) {
    int mk = o / 55, t = o % 55;
    int t0 = t, i = 0;
    while (t0 >= 10 - i) { t0 -= 10 - i; i++; }
    int n = i + t0;
    float acc = 0.f;
    for (int j = 0; j < DIN; j++)
      acc = fmaf(Wl[mk * DIN * 10 + j * 10 + i], Tl[mk * DIN * 10 + j * 10 + n], acc);
    if (i == n) acc += RIDGE;
    cand[t * NM + mk * BC + bc] = acc;
  }
}

// ---------------------------------------------------------------- shared logm epilogue
__device__ __forceinline__ void logm_epilogue(float* A, float* V,
                                              float* __restrict__ cand, int NM, int mat) {
  float f[10];
#pragma unroll
  for (int r = 0; r < 10; r++) f[r] = __logf(fmaxf(A[TIX(r, r)], EPSV));
#pragma unroll
  for (int i = 0; i < 10; i++) {
    float w[10];
#pragma unroll
    for (int r = 0; r < 10; r++) w[r] = V[i * 10 + r] * f[r];
#pragma unroll
    for (int n = i; n < 10; n++) {
      float acc = 0.f;
#pragma unroll
      for (int r = 0; r < 10; r++) acc = fmaf(w[r], V[n * 10 + r], acc);
      cand[TIX(i, n) * NM + mat] = acc;
    }
  }
}

// ---------------------------------------------------------------- logm from cand buffer (cell 0)
// 64-thread blocks: 384 blocks spread all 256 CUs (256-thread blocks gave only
// 96 blocks -> 96 CUs busy, ~2.7x worse per-CU load than cell-2).
__global__ __launch_bounds__(64) void k_logm(float* __restrict__ cand, int NM) {
  int mat = blockIdx.x * 64 + threadIdx.x;   // NM is a multiple of 64
  float A[55];
#pragma unroll
  for (int t = 0; t < 55; t++) A[t] = cand[t * NM + mat];
  float V[100];
  jacobi10(A, V);
  logm_epilogue(A, V, cand, NM, mat);
}

// ---------------------------------------------------------------- fused cand+logm (cells 1,2; DIN=10)
// S elem-major [e][BC] (written by k_expm) -> fully coalesced reads.
// 64-thread blocks (round 13: ~2% faster than 256, VGPR clean).
template <int BC>
__global__ __launch_bounds__(64) void k_candlogm(const float* __restrict__ Sin,
                                                 const float* __restrict__ Wop,
                                                 float* __restrict__ cand) {
  __shared__ float Wl[100];
  int tid = threadIdx.x;
  const int NM = 12 * BC;
  int mat = blockIdx.x * 64 + tid;
  int mk0 = (blockIdx.x * 64) / BC;      // 64 | BC -> uniform per block
  for (int i = tid; i < 100; i += 64) Wl[i] = Wop[mk0 * 100 + i];
  __syncthreads();
  int bc = mat % BC;
  const float* Sb = Sin + bc;            // elem-major: S[e*BC + bc]

  float U[100];
#pragma unroll
  for (int i = 0; i < 100; i++) U[i] = 0.f;
#pragma unroll
  for (int j = 0; j < 10; j++) {
    float sr[10];
#pragma unroll
    for (int l = 0; l < 10; l++) sr[l] = Sb[(j * 10 + l) * BC];
    float wr[10];
#pragma unroll
    for (int i = 0; i < 10; i++) wr[i] = Wl[j * 10 + i];
#pragma unroll
    for (int i = 0; i < 10; i++)
#pragma unroll
      for (int l = 0; l < 10; l++) U[i * 10 + l] = fmaf(wr[i], sr[l], U[i * 10 + l]);
  }
  float A[55];
#pragma unroll
  for (int t = 0; t < 55; t++) A[t] = 0.f;
#pragma unroll
  for (int i = 0; i < 10; i++) A[TIX(i, i)] = RIDGE;
#pragma unroll
  for (int l = 0; l < 10; l++) {
    float wr[10];
#pragma unroll
    for (int n = 0; n < 10; n++) wr[n] = Wl[l * 10 + n];
#pragma unroll
    for (int i = 0; i < 10; i++) {
      float u = U[i * 10 + l];
#pragma unroll
      for (int n = i; n < 10; n++) A[TIX(i, n)] = fmaf(u, wr[n], A[TIX(i, n)]);
    }
  }
  float V[100];
  jacobi10(A, V);
  logm_epilogue(A, V, cand, NM, mat);
}

// ---------------------------------------------------------------- sparsemax (per-thread, K=6)
__device__ __forceinline__ void sparsemax6(const float* __restrict__ a, int row, float* w) {
  float z[KOPS], zs[KOPS];
#pragma unroll
  for (int i = 0; i < KOPS; i++) { z[i] = a[row * KOPS + i]; zs[i] = z[i]; }
#pragma unroll
  for (int i = 0; i < KOPS; i++)
#pragma unroll
    for (int j = i + 1; j < KOPS; j++)
      if (zs[j] > zs[i]) { float tm = zs[i]; zs[i] = zs[j]; zs[j] = tm; }
  float acc = 0.f, zcp = 1.f; float cnt = 1.f;
#pragma unroll
  for (int i = 0; i < KOPS; i++) {
    acc += zs[i];
    if (1.0f + (float)(i + 1) * zs[i] > acc) { cnt = (float)(i + 1); zcp = acc; }
  }
  float tau = (zcp - 1.0f) / cnt;
#pragma unroll
  for (int i = 0; i < KOPS; i++) w[i] = fmaxf(z[i] - tau, 0.0f);
}

// ---------------------------------------------------------------- expm of weighted sum -> new S
// Output element-major [e][2*BC] -> fully coalesced stores, coalesced reads downstream.
template <int BC, int C>
__global__ __launch_bounds__(64) void k_expm(const float* __restrict__ L,
                                             const float* __restrict__ alphas, int row,
                                             float* __restrict__ Sout) {
  const int NM = 12 * BC;
  const int NE = 2 * BC;
  int id = blockIdx.x * 64 + threadIdx.x;  // id = m*BC + bc; 2*BC is a multiple of 64
  int m = id / BC;
  int bc = id % BC;
  float w[KOPS];
  sparsemax6(alphas, row, w);
  float A[55];
#pragma unroll
  for (int t = 0; t < 55; t++) {
    float acc = 0.f;
#pragma unroll
    for (int k2 = 0; k2 < KOPS; k2++) acc = fmaf(w[k2], L[t * NM + (m * KOPS + k2) * BC + bc], acc);
    A[t] = acc;
  }
  float V[100];
  jacobi10(A, V);
  float f[10];
#pragma unroll
  for (int r = 0; r < 10; r++) f[r] = __expf(A[TIX(r, r)]);
  int b = bc / C, c = bc % C;
  int idm = b * 2 * C + m * C + c;         // next stage's bc index
  float* out = Sout + idm;
#pragma unroll
  for (int i = 0; i < 10; i++) {
    float wv[10];
#pragma unroll
    for (int r = 0; r < 10; r++) wv[r] = V[i * 10 + r] * f[r];
#pragma unroll
    for (int n = i; n < 10; n++) {
      float acc = 0.f;
#pragma unroll
      for (int r = 0; r < 10; r++) acc = fmaf(wv[r], V[n * 10 + r], acc);
      out[(i * 10 + n) * NE] = acc;
      if (n != i) out[(n * 10 + i) * NE] = acc;
    }
  }
}

// ---------------------------------------------------------------- final: Z = sum w_k L_k fed straight to classifier
// Identity: out = logm(expm(Z)) = Z for symmetric Z — the final expm + logm
// (2x 16384 jacobis) cancel exactly. EPSV clamp inert (eigs >= log(RIDGE)).
__global__ __launch_bounds__(64) void k_final_direct(const float* __restrict__ L,
                                                     const float* __restrict__ alphas,
                                                     const float* __restrict__ Wc,
                                                     const float* __restrict__ bcv,
                                                     float* __restrict__ out) {
  const int BC = 4 * NB;
  const int NM = 12 * BC;
  int id = blockIdx.x * 64 + threadIdx.x;  // b*8+ch, total 16384
  int ch = id & 7;
  int b = id >> 3;
  int m = ch >> 2, j = ch & 3;
  int bc = b * 4 + j;
  float w[KOPS];
  sparsemax6(alphas, 2, w);
  const float* Lb = L + (size_t)(m * KOPS) * BC + bc;
  float Z[55];
#pragma unroll
  for (int t = 0; t < 55; t++) {
    float acc = 0.f;
#pragma unroll
    for (int k2 = 0; k2 < KOPS; k2++) acc = fmaf(w[k2], Lb[(size_t)t * NM + k2 * BC], acc);
    Z[t] = acc;
  }
  float acc[10];
#pragma unroll
  for (int c2 = 0; c2 < 10; c2++) acc[c2] = 0.f;
  const float* wbase = Wc + ch * 1000;     // row (ch*100 + i*10 + n), 10 cols
#pragma unroll
  for (int i = 0; i < 10; i++) {
#pragma unroll
    for (int n = 0; n < 10; n++) {
      float lv = (i <= n) ? Z[TIX(i, n)] : Z[TIX(n, i)];
      const float* wrow = wbase + (i * 10 + n) * 10;
#pragma unroll
      for (int h = 0; h < 5; h++) {
        float2 wc2 = *(const float2*)(wrow + 2 * h);
        acc[2 * h]     = fmaf(lv, wc2.x, acc[2 * h]);
        acc[2 * h + 1] = fmaf(lv, wc2.y, acc[2 * h + 1]);
      }
    }
  }
  // reduce over the 8 channel lanes (lanes id&7 within each group of 8)
#pragma unroll
  for (int mk = 1; mk < 8; mk <<= 1) {
#pragma unroll
    for (int c2 = 0; c2 < 10; c2++) acc[c2] += __shfl_xor(acc[c2], mk, 8);
  }
  if (ch == 0) {
#pragma unroll
    for (int c2 = 0; c2 < 10; c2++) out[b * 10 + c2] = acc[c2] + bcv[c2];
  }
}

// ---------------------------------------------------------------- launch
extern "C" void kernel_launch(void* const* d_in, const int* in_sizes, int n_in,
                              void* d_out, int out_size, void* d_ws, size_t ws_size,
                              hipStream_t stream) {
  const float* x      = (const float*)d_in[0];
  const float* Wst    = (const float*)d_in[1];
  const float* Wop0   = (const float*)d_in[2];
  const float* Wop1   = (const float*)d_in[3];
  const float* Wop2   = (const float*)d_in[4];
  const float* alphas = (const float*)d_in[5];
  const float* Wcls   = (const float*)d_in[6];
  const float* bcls   = (const float*)d_in[7];
  float* out = (float*)d_out;

  // workspace layout (floats): Sa(2048*800) | Sb(2048*800) | cand(55*12*2048*4)
  float* ws   = (float*)d_ws;
  float* Sa   = ws;
  float* Sb   = Sa + (size_t)NB * 800;
  float* cand = Sb + (size_t)NB * 800;

  k_cov_stem<<<NB, 256, 0, stream>>>(x, Wst, Sa);

  // cell 0: S (B,1,20,20) -> (B,2,10,10)   (DIN=20: split cand/logm path)
  k_cand20<<<NB, 256, 0, stream>>>(Sa, Wop0, cand, NB);
  k_logm<<<(12 * NB) / 64, 64, 0, stream>>>(cand, 12 * NB);
  k_expm<NB, 1><<<(2 * NB) / 64, 64, 0, stream>>>(cand, alphas, 0, Sb);

  // cell 1: (B,2,10,10) -> (B,4,10,10)   (fused cand+logm, elem-major S)
  k_candlogm<NB * 2><<<(12 * NB * 2) / 64, 64, 0, stream>>>(Sb, Wop1, cand);
  k_expm<NB * 2, 2><<<(4 * NB) / 64, 64, 0, stream>>>(cand, alphas, 1, Sa);

  // cell 2: (B,4,10,10) -> (B,8,10,10)
  k_candlogm<NB * 4><<<(12 * NB * 4) / 64, 64, 0, stream>>>(Sa, Wop2, cand);

  // final: logm(expm(Z)) = Z — weighted L-sum straight into classifier
  k_final_direct<<<(8 * NB) / 64, 64, 0, stream>>>(cand, alphas, Wcls, bcls, out);
}